// Round 1
// baseline (99.492 us; speedup 1.0000x reference)
//
#include <hip/hip_runtime.h>
#include <math.h>

// Problem constants (from reference): B=4, S=4096, H=768, L=8, fp32.
constexpr int kB = 4, kS = 4096, kH = 768, kL = 8;
constexpr int kBS = kB * kS;                       // 16384 rows
constexpr size_t kLayerStride = (size_t)kBS * kH;  // floats between layers
constexpr int kNChunk = 32;
constexpr int kChunk = kH / kNChunk;               // 24
constexpr float kInvSqrtH = 0.03608439182435161f;  // 1/sqrt(768)

// Stage 1: partial qW[j] over an i-chunk. grid=(H/256, kNChunk), block=256.
__global__ void qw_partial_kernel(const float* __restrict__ Wk,
                                  const float* __restrict__ q,
                                  float* __restrict__ part) {
    int j = blockIdx.x * 256 + threadIdx.x;  // 0..767, coalesced over j
    int i0 = blockIdx.y * kChunk;
    float s = 0.f;
#pragma unroll
    for (int k = 0; k < kChunk; ++k)
        s = fmaf(q[i0 + k], Wk[(size_t)(i0 + k) * kH + j], s);
    part[blockIdx.y * kH + j] = s;
}

// Stage 2: reduce partials, fold in 1/sqrt(H). grid=H/256, block=256.
__global__ void qw_reduce_kernel(const float* __restrict__ part,
                                 float* __restrict__ qw) {
    int j = blockIdx.x * 256 + threadIdx.x;
    float s = 0.f;
#pragma unroll
    for (int c = 0; c < kNChunk; ++c) s += part[c * kH + j];
    qw[j] = s * kInvSqrtH;
}

// Main fused kernel: one 64-lane wave per (b,s) row. Row (8 layers x 768 f32
// = 24 KB) is held in registers: lane holds 3 float4 per layer. Dots are
// butterfly-reduced across the wave; softmax over L=8 is lane-local after
// the reduce; weighted sum is written back as float4 (coalesced).
__global__ void attn_fused_kernel(const float* __restrict__ pre,
                                  const float* __restrict__ qw,
                                  float* __restrict__ out) {
    const int wid = threadIdx.x >> 6;
    const int lane = threadIdx.x & 63;
    const int bs = blockIdx.x * 4 + wid;

    const float4* __restrict__ row =
        reinterpret_cast<const float4*>(pre) + (size_t)bs * (kH / 4);
    const float4* __restrict__ qw4 = reinterpret_cast<const float4*>(qw);

    float4 qv[3];
#pragma unroll
    for (int c = 0; c < 3; ++c) qv[c] = qw4[c * 64 + lane];

    float4 v[kL][3];
    float d[kL];
#pragma unroll
    for (int l = 0; l < kL; ++l) {
        const float4* p = row + (size_t)l * (kLayerStride / 4);
        float s = 0.f;
#pragma unroll
        for (int c = 0; c < 3; ++c) {
            float4 t = p[c * 64 + lane];  // 64 lanes x 16B = 1 KB contiguous
            v[l][c] = t;
            s = fmaf(t.x, qv[c].x, s);
            s = fmaf(t.y, qv[c].y, s);
            s = fmaf(t.z, qv[c].z, s);
            s = fmaf(t.w, qv[c].w, s);
        }
        d[l] = s;
    }

    // Butterfly reduce: all 64 lanes end with the full per-layer dots.
#pragma unroll
    for (int off = 32; off > 0; off >>= 1) {
#pragma unroll
        for (int l = 0; l < kL; ++l) d[l] += __shfl_xor(d[l], off, 64);
    }

    // Softmax over L=8 (lane-local, identical in all lanes).
    float m = d[0];
#pragma unroll
    for (int l = 1; l < kL; ++l) m = fmaxf(m, d[l]);
    float w[kL], sum = 0.f;
#pragma unroll
    for (int l = 0; l < kL; ++l) { w[l] = __expf(d[l] - m); sum += w[l]; }
    float inv = 1.f / sum;
#pragma unroll
    for (int l = 0; l < kL; ++l) w[l] *= inv;

    float4* __restrict__ o4 =
        reinterpret_cast<float4*>(out) + (size_t)bs * (kH / 4);
#pragma unroll
    for (int c = 0; c < 3; ++c) {
        float4 o = make_float4(0.f, 0.f, 0.f, 0.f);
#pragma unroll
        for (int l = 0; l < kL; ++l) {
            o.x = fmaf(w[l], v[l][c].x, o.x);
            o.y = fmaf(w[l], v[l][c].y, o.y);
            o.z = fmaf(w[l], v[l][c].z, o.z);
            o.w = fmaf(w[l], v[l][c].w, o.w);
        }
        o4[c * 64 + lane] = o;
    }
}

extern "C" void kernel_launch(void* const* d_in, const int* in_sizes, int n_in,
                              void* d_out, int out_size, void* d_ws, size_t ws_size,
                              hipStream_t stream) {
    // setup_inputs order: 0=current_output (UNUSED by reference), 1=preceding,
    // 2=W_key, 3=query. All fp32.
    const float* pre = (const float*)d_in[1];
    const float* Wk  = (const float*)d_in[2];
    const float* q   = (const float*)d_in[3];
    float* out = (float*)d_out;

    // Workspace layout: qW [768 floats] | partials [32*768 floats] (~101 KB).
    float* qw   = (float*)d_ws;
    float* part = qw + kH;

    dim3 g1(kH / 256, kNChunk);
    qw_partial_kernel<<<g1, 256, 0, stream>>>(Wk, q, part);
    qw_reduce_kernel<<<kH / 256, 256, 0, stream>>>(part, qw);
    attn_fused_kernel<<<kBS / 4, 256, 0, stream>>>(pre, qw, out);
}

// Round 3
// 83.805 us; speedup vs baseline: 1.1872x; 1.1872x over previous
//
#include <hip/hip_runtime.h>
#include <math.h>

// Problem constants (from reference): B=4, S=4096, H=768, L=8, fp32.
constexpr int kB = 4, kS = 4096, kH = 768, kL = 8;
constexpr int kBS = kB * kS;                       // 16384 rows
constexpr size_t kLayerStride = (size_t)kBS * kH;  // floats between layers
constexpr int kNChunk = 32;
constexpr int kChunk = kH / kNChunk;               // 24
constexpr float kInvSqrtH = 0.03608439182435161f;  // 1/sqrt(768)

// Clang ext-vector (NOT HIP_vector_type) — required by __builtin_nontemporal_*.
typedef float f32x4 __attribute__((ext_vector_type(4)));

// Stage 1: partial qW[j] over an i-chunk. grid=(H/256, kNChunk), block=256.
__global__ void qw_partial_kernel(const float* __restrict__ Wk,
                                  const float* __restrict__ q,
                                  float* __restrict__ part) {
    int j = blockIdx.x * 256 + threadIdx.x;  // 0..767, coalesced over j
    int i0 = blockIdx.y * kChunk;
    float s = 0.f;
#pragma unroll
    for (int k = 0; k < kChunk; ++k)
        s = fmaf(q[i0 + k], Wk[(size_t)(i0 + k) * kH + j], s);
    part[blockIdx.y * kH + j] = s;
}

// Stage 2: reduce partials, fold in 1/sqrt(H). grid=H/256, block=256.
__global__ void qw_reduce_kernel(const float* __restrict__ part,
                                 float* __restrict__ qw) {
    int j = blockIdx.x * 256 + threadIdx.x;
    float s = 0.f;
#pragma unroll
    for (int c = 0; c < kNChunk; ++c) s += part[c * kH + j];
    qw[j] = s * kInvSqrtH;
}

// Main fused kernel: one 64-lane wave per (b,s) row. Phases made explicit:
//   P1: issue all 24 nontemporal f32x4 loads (row held in 96 VGPRs)
//   P2: dots, c-outer so only one qv vector is live at a time (peak VGPR<128)
//   P3: butterfly reduce + lane-local softmax over L=8
//   P4: weighted sum, nontemporal f32x4 store
// __launch_bounds__(256,4): 4 waves/SIMD — keep allocator under the 128 cliff.
__global__ __launch_bounds__(256, 4) void attn_fused_kernel(
        const float* __restrict__ pre,
        const float* __restrict__ qw,
        float* __restrict__ out) {
    const int wid = threadIdx.x >> 6;
    const int lane = threadIdx.x & 63;
    const int bs = blockIdx.x * 4 + wid;

    const f32x4* __restrict__ row =
        reinterpret_cast<const f32x4*>(pre) + (size_t)bs * (kH / 4);
    const f32x4* __restrict__ qw4 = reinterpret_cast<const f32x4*>(qw);

    // P1 — all loads in flight (24 KB/wave outstanding).
    f32x4 v[kL][3];
#pragma unroll
    for (int l = 0; l < kL; ++l) {
        const f32x4* p = row + (size_t)l * (kLayerStride / 4);
#pragma unroll
        for (int c = 0; c < 3; ++c)
            v[l][c] = __builtin_nontemporal_load(p + c * 64 + lane);
    }

    // P2 — per-lane partial dots.
    float d[kL];
#pragma unroll
    for (int l = 0; l < kL; ++l) d[l] = 0.f;
#pragma unroll
    for (int c = 0; c < 3; ++c) {
        const f32x4 qv = qw4[c * 64 + lane];  // L2-broadcast, one live at a time
#pragma unroll
        for (int l = 0; l < kL; ++l) {
            d[l] = fmaf(v[l][c].x, qv.x, d[l]);
            d[l] = fmaf(v[l][c].y, qv.y, d[l]);
            d[l] = fmaf(v[l][c].z, qv.z, d[l]);
            d[l] = fmaf(v[l][c].w, qv.w, d[l]);
        }
    }

    // P3 — butterfly reduce: all 64 lanes end with full per-layer dots.
#pragma unroll
    for (int off = 32; off > 0; off >>= 1) {
#pragma unroll
        for (int l = 0; l < kL; ++l) d[l] += __shfl_xor(d[l], off, 64);
    }

    // Softmax over L=8 (lane-local, identical in all lanes).
    float m = d[0];
#pragma unroll
    for (int l = 1; l < kL; ++l) m = fmaxf(m, d[l]);
    float sum = 0.f;
#pragma unroll
    for (int l = 0; l < kL; ++l) { d[l] = __expf(d[l] - m); sum += d[l]; }
    const float inv = 1.f / sum;
#pragma unroll
    for (int l = 0; l < kL; ++l) d[l] *= inv;

    // P4 — weighted sum + coalesced NT store.
    f32x4* __restrict__ o4 =
        reinterpret_cast<f32x4*>(out) + (size_t)bs * (kH / 4);
#pragma unroll
    for (int c = 0; c < 3; ++c) {
        f32x4 o = {0.f, 0.f, 0.f, 0.f};
#pragma unroll
        for (int l = 0; l < kL; ++l) {
            o.x = fmaf(d[l], v[l][c].x, o.x);
            o.y = fmaf(d[l], v[l][c].y, o.y);
            o.z = fmaf(d[l], v[l][c].z, o.z);
            o.w = fmaf(d[l], v[l][c].w, o.w);
        }
        __builtin_nontemporal_store(o, o4 + c * 64 + lane);
    }
}

extern "C" void kernel_launch(void* const* d_in, const int* in_sizes, int n_in,
                              void* d_out, int out_size, void* d_ws, size_t ws_size,
                              hipStream_t stream) {
    // setup_inputs order: 0=current_output (UNUSED by reference), 1=preceding,
    // 2=W_key, 3=query. All fp32.
    const float* pre = (const float*)d_in[1];
    const float* Wk  = (const float*)d_in[2];
    const float* q   = (const float*)d_in[3];
    float* out = (float*)d_out;

    // Workspace layout: qW [768 floats] | partials [32*768 floats] (~101 KB).
    float* qw   = (float*)d_ws;
    float* part = qw + kH;

    dim3 g1(kH / 256, kNChunk);
    qw_partial_kernel<<<g1, 256, 0, stream>>>(Wk, q, part);
    qw_reduce_kernel<<<kH / 256, 256, 0, stream>>>(part, qw);
    attn_fused_kernel<<<kBS / 4, 256, 0, stream>>>(pre, qw, out);
}